// Round 12
// baseline (307.837 us; speedup 1.0000x reference)
//
#include <hip/hip_runtime.h>

#define NUM_USERS 100000
#define NUM_ITEMS 50000
#define N_TOTAL   150000
#define LATENT    64
#define BATCH     16384
#define BROWS     512                 // rows per bucket
#define NB        293                 // ceil(N_TOTAL / BROWS)
#define CAP       16384               // per-bucket slab capacity (count ~13.6k +- 120, +23 sigma)
#define P1_T      512                 // partition threads
#define P1_C      2048                // partition1 edges per block (25KB LDS -> 4 blocks/CU)
#define CVT_B     2344                // convert blocks (2.4M float4 items, 2/thread)
#define INIT_B    512                 // init_acc blocks (BATCH*16 float4 threads)
#define GATH_B    1024                // gather blocks (BATCH*16 threads @256)

typedef unsigned int u32;
typedef unsigned short u16;

__device__ __forceinline__ u16 f32_to_bf16(float f) {
    u32 u = __float_as_uint(f);
    u32 r = (u + 0x7FFFu + ((u >> 16) & 1u)) >> 16;   // round-to-nearest-even
    return (u16)r;
}
__device__ __forceinline__ float bf16_lo(u32 w) { return __uint_as_float(w << 16); }
__device__ __forceinline__ float bf16_hi(u32 w) { return __uint_as_float(w & 0xFFFF0000u); }

__device__ __forceinline__ void fma4(float acc[4], uint2 xv, float v) {
    acc[0] = fmaf(v, bf16_lo(xv.x), acc[0]);
    acc[1] = fmaf(v, bf16_hi(xv.x), acc[1]);
    acc[2] = fmaf(v, bf16_lo(xv.y), acc[2]);
    acc[3] = fmaf(v, bf16_hi(xv.y), acc[3]);
}

// ---- wave-level inclusive scan (64 lanes) ----
__device__ __forceinline__ int wave_incl_scan(int v, int lane) {
    #pragma unroll
    for (int d = 1; d < 64; d <<= 1) {
        int t = __shfl_up(v, d, 64);
        if (lane >= d) v += t;
    }
    return v;
}

// ---- 512-thread block exclusive scan; wsum is LDS int[8]; 2 barriers ----
__device__ __forceinline__ int block_excl_scan_512(int v, int t, int* wsum) {
    int lane = t & 63, w = t >> 6;
    int incl = wave_incl_scan(v, lane);
    if (lane == 63) wsum[w] = incl;
    __syncthreads();
    if (t == 0) {
        int acc = 0;
        #pragma unroll
        for (int k = 0; k < 8; ++k) { int c = wsum[k]; wsum[k] = acc; acc += c; }
    }
    __syncthreads();
    return wsum[w] + incl - v;
}

// =================== fat kernel A: p1 | convert | init_acc, INTERLEAVED ===================
// block->role mapping alternates p1 and aux blocks so that streaming convert blocks
// co-reside with latency-bound p1 blocks on every CU (roles overlap instead of summing).
__global__ void __launch_bounds__(P1_T)
fatA_kernel(const int* __restrict__ rows, const int* __restrict__ cols,
            const float* __restrict__ vals,
            int* __restrict__ ccur, uint2* __restrict__ packed0, u16* __restrict__ klab,
            const float* __restrict__ ue, const float* __restrict__ ie,
            u16* __restrict__ emb0,
            const int* __restrict__ users, const int* __restrict__ items,
            float* __restrict__ u_acc, float* __restrict__ i_acc,
            int nnz, int np1) {
    __shared__ u32 skey[P1_C];
    __shared__ u32 sval[P1_C];
    __shared__ u16 sbucket[P1_C];
    __shared__ int cnt[NB];
    __shared__ int lstart[NB];
    __shared__ int lcur[NB];
    __shared__ int gbase[NB];
    __shared__ int wsum[8];

    int t = threadIdx.x;
    int bid = blockIdx.x;
    const int naux = CVT_B + INIT_B;

    // interleaved role mapping (np1 <= naux here: 1954 vs 2856)
    int role, rid;
    if (bid < 2 * np1) { role = bid & 1; rid = bid >> 1; }        // even->p1, odd->aux
    else              { role = 1;        rid = np1 + (bid - 2 * np1); }

    if (role == 0) {
        // ---------------- partition1 role ----------------
        int base = rid * P1_C;
        int chunkN = nnz - base; if (chunkN > P1_C) chunkN = P1_C;

        for (int i = t; i < NB; i += P1_T) cnt[i] = 0;
        __syncthreads();

        int er[4]; u32 ek[4]; u32 ev[4];
        #pragma unroll
        for (int k = 0; k < 4; ++k) {
            int e = base + k * P1_T + t;
            bool ok = (k * P1_T + t) < chunkN;
            int r = ok ? rows[e] : 0;
            er[k] = ok ? (r >> 9) : -1;
            if (ok) {
                ek[k] = (u32)cols[e] | ((u32)(r & (BROWS - 1)) << 18);
                ev[k] = __float_as_uint(vals[e]);
                atomicAdd(&cnt[er[k]], 1);
            }
        }
        __syncthreads();

        int v = (t < NB) ? cnt[t] : 0;
        int excl = block_excl_scan_512(v, t, wsum);
        if (t < NB) {
            lstart[t] = excl;
            lcur[t] = excl;
            gbase[t] = v ? atomicAdd(&ccur[t], v) : 0;
        }
        __syncthreads();

        #pragma unroll
        for (int k = 0; k < 4; ++k) {
            if (er[k] >= 0) {
                int pos = atomicAdd(&lcur[er[k]], 1);
                skey[pos] = ek[k];
                sval[pos] = ev[k];
                sbucket[pos] = (u16)er[k];
            }
        }
        __syncthreads();

        for (int idx = t; idx < chunkN; idx += P1_T) {
            int b2 = sbucket[idx];
            size_t gp = (size_t)b2 * CAP + gbase[b2] + (idx - lstart[b2]);
            u32 key = skey[idx];
            packed0[gp] = make_uint2(key, sval[idx]);
            klab[gp] = (u16)(key >> 18);
        }
    } else if (rid < CVT_B) {
        // ---------------- convert role: f32 -> bf16, 2 float4 items per thread ----------------
        const int n4 = N_TOTAL * LATENT / 4;
        const int ub = NUM_USERS * LATENT / 4;
        const int T  = CVT_B * P1_T;
        int g = rid * P1_T + t;
        #pragma unroll
        for (int rep = 0; rep < 2; ++rep) {
            int i = g + rep * T;
            if (i < n4) {
                float4 f = (i < ub) ? reinterpret_cast<const float4*>(ue)[i]
                                    : reinterpret_cast<const float4*>(ie)[i - ub];
                ushort4 o;
                o.x = f32_to_bf16(f.x); o.y = f32_to_bf16(f.y);
                o.z = f32_to_bf16(f.z); o.w = f32_to_bf16(f.w);
                reinterpret_cast<ushort4*>(emb0)[i] = o;
            }
        }
    } else {
        // ---------------- init_acc role: float4 per thread ----------------
        int g = (rid - CVT_B) * P1_T + t;           // 0 .. BATCH*16-1
        int b = g >> 4, dq = (g & 15) << 2;
        if (b < BATCH) {
            reinterpret_cast<float4*>(u_acc + (size_t)b * LATENT + dq)[0] =
                reinterpret_cast<const float4*>(ue + (size_t)users[b] * LATENT + dq)[0];
            reinterpret_cast<float4*>(i_acc + (size_t)b * LATENT + dq)[0] =
                reinterpret_cast<const float4*>(ie + (size_t)items[b] * LATENT + dq)[0];
        }
    }
}

// ---- pass 2: self-scanning per-bucket counting sort; emits rowptr + compact edges ----
__global__ void __launch_bounds__(BROWS)
partition2_kernel(const int* __restrict__ ccur, const uint2* __restrict__ packed0,
                  const u16* __restrict__ klab,
                  uint2* __restrict__ edges, int* __restrict__ rowptr, int nnz) {
    __shared__ int cnt[BROWS];
    __shared__ int cur[BROWS];
    __shared__ int wsum[8];
    __shared__ int sOutb;
    int b = blockIdx.x;
    int t = threadIdx.x;

    // self-scan of the 293 bucket counts -> this bucket's output base
    int cv = (t < NB) ? ccur[t] : 0;
    int cexcl = block_excl_scan_512(cv, t, wsum);
    if (t == b) sOutb = cexcl;
    cnt[t] = 0;
    __syncthreads();
    int outb = sOutb;
    int count = ccur[b];

    const uint2* src = packed0 + (size_t)b * CAP;
    const u16*   kl  = klab + (size_t)b * CAP;
    // histogram from the compact 2B key stream
    for (int i = t; i < count; i += 2 * BROWS) {
        u16 k0 = kl[i];
        int i2 = i + BROWS;
        if (i2 < count) {
            u16 k1 = kl[i2];
            atomicAdd(&cnt[k0], 1);
            atomicAdd(&cnt[k1], 1);
        } else {
            atomicAdd(&cnt[k0], 1);
        }
    }
    __syncthreads();
    int v = cnt[t];
    int excl = block_excl_scan_512(v, t, wsum);
    cur[t] = excl;
    int r = (b << 9) + t;
    if (r < N_TOTAL) rowptr[r] = outb + excl;
    if (b == NB - 1 && t == 0) rowptr[N_TOTAL] = nnz;
    __syncthreads();
    for (int i = t; i < count; i += 2 * BROWS) {
        uint2 p0 = src[i];
        int i2 = i + BROWS;
        if (i2 < count) {
            uint2 p1 = src[i2];
            int pos0 = outb + atomicAdd(&cur[p0.x >> 18], 1);
            int pos1 = outb + atomicAdd(&cur[p1.x >> 18], 1);
            edges[pos0] = make_uint2(p0.x & 0x3FFFFu, p0.y);
            edges[pos1] = make_uint2(p1.x & 0x3FFFFu, p1.y);
        } else {
            int pos0 = outb + atomicAdd(&cur[p0.x >> 18], 1);
            edges[pos0] = make_uint2(p0.x & 0x3FFFFu, p0.y);
        }
    }
}

// ---- row tail: 8-edge then guarded 4-edge loops (no reduce) ----
__device__ __forceinline__ void row_tail(const uint2* __restrict__ edges,
                                         const u16* __restrict__ x,
                                         int i, int e, int j, int q, float acc[4]) {
    for (; i + 8 <= e; i += 8) {
        uint2 e0 = edges[i + j];
        uint2 e1 = edges[i + 4 + j];
        uint2 x0 = *reinterpret_cast<const uint2*>(x + (size_t)e0.x * LATENT + q);
        uint2 x1 = *reinterpret_cast<const uint2*>(x + (size_t)e1.x * LATENT + q);
        fma4(acc, x0, __uint_as_float(e0.y));
        fma4(acc, x1, __uint_as_float(e1.y));
    }
    for (; i < e; i += 4) {
        // memory-safe: edges has >=16 zero-padded entries past nnz; reading the
        // next row's edge is fine because v is forced to 0 for out-of-row slots
        uint2 e0 = edges[i + j];
        float v0 = (i + j < e) ? __uint_as_float(e0.y) : 0.f;
        uint2 x0 = *reinterpret_cast<const uint2*>(x + (size_t)e0.x * LATENT + q);
        fma4(acc, x0, v0);
    }
}

// ---- single-row SpMM core (used by batch kernel) ----
__device__ __forceinline__ void spmm_row(const uint2* __restrict__ edges,
                                         const u16* __restrict__ x,
                                         int s, int e, int lane, float acc[4]) {
    int j = lane >> 4;
    int q = (lane & 15) << 2;
    acc[0] = acc[1] = acc[2] = acc[3] = 0.f;
    int i = s;
    for (; i + 16 <= e; i += 16) {
        uint2 e0 = edges[i + j];
        uint2 e1 = edges[i + 4 + j];
        uint2 e2 = edges[i + 8 + j];
        uint2 e3 = edges[i + 12 + j];
        uint2 x0 = *reinterpret_cast<const uint2*>(x + (size_t)e0.x * LATENT + q);
        uint2 x1 = *reinterpret_cast<const uint2*>(x + (size_t)e1.x * LATENT + q);
        uint2 x2 = *reinterpret_cast<const uint2*>(x + (size_t)e2.x * LATENT + q);
        uint2 x3 = *reinterpret_cast<const uint2*>(x + (size_t)e3.x * LATENT + q);
        fma4(acc, x0, __uint_as_float(e0.y));
        fma4(acc, x1, __uint_as_float(e1.y));
        fma4(acc, x2, __uint_as_float(e2.y));
        fma4(acc, x3, __uint_as_float(e3.y));
    }
    row_tail(edges, x, i, e, j, q, acc);
    #pragma unroll
    for (int k = 0; k < 4; ++k) {
        acc[k] += __shfl_xor(acc[k], 16, 64);
        acc[k] += __shfl_xor(acc[k], 32, 64);
    }
}

// ---- two-row SpMM body (writes bf16 rows r0, r0+1) ----
__device__ __forceinline__ void spmm_two_rows(const int* __restrict__ rowptr,
                                              const uint2* __restrict__ edges,
                                              const u16* __restrict__ x,
                                              u16* __restrict__ y,
                                              int wid, int lane) {
    int r0 = wid * 2;
    int j = lane >> 4;
    int q = (lane & 15) << 2;
    int i0 = rowptr[r0];
    int e0 = rowptr[r0 + 1];
    int i1 = e0;
    int e1 = rowptr[r0 + 2];
    float a0[4] = {0.f, 0.f, 0.f, 0.f};
    float a1[4] = {0.f, 0.f, 0.f, 0.f};

    while (i0 + 8 <= e0 && i1 + 8 <= e1) {
        uint2 p00 = edges[i0 + j];
        uint2 p01 = edges[i0 + 4 + j];
        uint2 p10 = edges[i1 + j];
        uint2 p11 = edges[i1 + 4 + j];
        uint2 g00 = *reinterpret_cast<const uint2*>(x + (size_t)p00.x * LATENT + q);
        uint2 g01 = *reinterpret_cast<const uint2*>(x + (size_t)p01.x * LATENT + q);
        uint2 g10 = *reinterpret_cast<const uint2*>(x + (size_t)p10.x * LATENT + q);
        uint2 g11 = *reinterpret_cast<const uint2*>(x + (size_t)p11.x * LATENT + q);
        fma4(a0, g00, __uint_as_float(p00.y));
        fma4(a0, g01, __uint_as_float(p01.y));
        fma4(a1, g10, __uint_as_float(p10.y));
        fma4(a1, g11, __uint_as_float(p11.y));
        i0 += 8;
        i1 += 8;
    }
    row_tail(edges, x, i0, e0, j, q, a0);
    row_tail(edges, x, i1, e1, j, q, a1);

    #pragma unroll
    for (int k = 0; k < 4; ++k) {
        a0[k] += __shfl_xor(a0[k], 16, 64);
        a0[k] += __shfl_xor(a0[k], 32, 64);
        a1[k] += __shfl_xor(a1[k], 16, 64);
        a1[k] += __shfl_xor(a1[k], 32, 64);
    }
    if (lane < 16) {
        u32 w0 = (u32)f32_to_bf16(a0[0]) | ((u32)f32_to_bf16(a0[1]) << 16);
        u32 w1 = (u32)f32_to_bf16(a0[2]) | ((u32)f32_to_bf16(a0[3]) << 16);
        *reinterpret_cast<uint2*>(y + (size_t)r0 * LATENT + (lane << 2)) = make_uint2(w0, w1);
        u32 w2 = (u32)f32_to_bf16(a1[0]) | ((u32)f32_to_bf16(a1[1]) << 16);
        u32 w3 = (u32)f32_to_bf16(a1[2]) | ((u32)f32_to_bf16(a1[3]) << 16);
        *reinterpret_cast<uint2*>(y + (size_t)(r0 + 1) * LATENT + (lane << 2)) = make_uint2(w2, w3);
    }
}

// ---- gather-acc role body: uint2 (4 bf16 dims) per thread ----
__device__ __forceinline__ void gather_role(const u16* __restrict__ emb,
                                            const int* __restrict__ users,
                                            const int* __restrict__ items,
                                            float* __restrict__ u_acc,
                                            float* __restrict__ i_acc, int g) {
    int b = g >> 4, dq = (g & 15) << 2;
    if (b >= BATCH) return;
    uint2 xu = *reinterpret_cast<const uint2*>(emb + (size_t)users[b] * LATENT + dq);
    uint2 xi = *reinterpret_cast<const uint2*>(emb + ((size_t)items[b] + NUM_USERS) * LATENT + dq);
    float4* pu = reinterpret_cast<float4*>(u_acc + (size_t)b * LATENT + dq);
    float4* pi = reinterpret_cast<float4*>(i_acc + (size_t)b * LATENT + dq);
    float4 ou = *pu, oi = *pi;
    ou.x += bf16_lo(xu.x); ou.y += bf16_hi(xu.x); ou.z += bf16_lo(xu.y); ou.w += bf16_hi(xu.y);
    oi.x += bf16_lo(xi.x); oi.y += bf16_hi(xi.x); oi.z += bf16_lo(xi.y); oi.w += bf16_hi(xi.y);
    *pu = ou; *pi = oi;
}

// ---- spmm layer 1 (pure) ----
__global__ void spmm_kernel(const int* __restrict__ rowptr, const uint2* __restrict__ edges,
                            const u16* __restrict__ x, u16* __restrict__ y) {
    int wid = blockIdx.x * 4 + (threadIdx.x >> 6);
    spmm_two_rows(rowptr, edges, x, y, wid, threadIdx.x & 63);
}

// ---- spmm layer 2 + gather_acc(layer-1 output) fat kernel (disjoint buffers: safe) ----
__global__ void spmm_gather_kernel(const int* __restrict__ rowptr, const uint2* __restrict__ edges,
                                   const u16* __restrict__ x, u16* __restrict__ y,
                                   const int* __restrict__ users, const int* __restrict__ items,
                                   float* __restrict__ u_acc, float* __restrict__ i_acc,
                                   int nspmm) {
    int bid = blockIdx.x;
    if (bid < nspmm) {
        int wid = bid * 4 + (threadIdx.x >> 6);
        spmm_two_rows(rowptr, edges, x, y, wid, threadIdx.x & 63);
    } else {
        gather_role(x, users, items, u_acc, i_acc, (bid - nspmm) * 256 + threadIdx.x);
    }
}

// ---- layer 3: batch-rows-only SpMM with layer-2 gather FOLDED into the epilogue ----
// (single RMW per u_acc/i_acc address in this kernel -> no race)
__global__ void spmm_batch_kernel(const int* __restrict__ rowptr, const uint2* __restrict__ edges,
                                  const u16* __restrict__ x,
                                  const int* __restrict__ users, const int* __restrict__ items,
                                  float* __restrict__ u_acc, float* __restrict__ i_acc) {
    int slot = blockIdx.x * 4 + (threadIdx.x >> 6);   // 0 .. 2*BATCH-1
    int lane = threadIdx.x & 63;
    int row = (slot < BATCH) ? users[slot] : (NUM_USERS + items[slot - BATCH]);
    int s = rowptr[row], e = rowptr[row + 1];
    float acc[4];
    spmm_row(edges, x, s, e, lane, acc);
    if (lane < 16) {
        // layer-2 contribution: this row's own embedding (input x of this kernel)
        uint2 xr = *reinterpret_cast<const uint2*>(x + (size_t)row * LATENT + (lane << 2));
        float* dst = (slot < BATCH) ? (u_acc + (size_t)slot * LATENT)
                                    : (i_acc + (size_t)(slot - BATCH) * LATENT);
        float4* p = reinterpret_cast<float4*>(dst + (lane << 2));
        float4 old = *p;
        old.x += acc[0] + bf16_lo(xr.x);
        old.y += acc[1] + bf16_hi(xr.x);
        old.z += acc[2] + bf16_lo(xr.y);
        old.w += acc[3] + bf16_hi(xr.y);
        *p = old;
    }
}

// ---- gamma[b] = dot(u_acc[b], i_acc[b]) / 16 ; 8 rows per 512-thread block ----
__global__ void dot_kernel(const float* __restrict__ u_acc,
                           const float* __restrict__ i_acc,
                           float* __restrict__ out) {
    int b = blockIdx.x * 8 + (threadIdx.x >> 6);
    int d = threadIdx.x & 63;
    float p = u_acc[b * 64 + d] * i_acc[b * 64 + d];
    #pragma unroll
    for (int off = 32; off; off >>= 1) p += __shfl_down(p, off, 64);
    if (d == 0) out[b] = p * (1.0f / 16.0f);
}

extern "C" void kernel_launch(void* const* d_in, const int* in_sizes, int n_in,
                              void* d_out, int out_size, void* d_ws, size_t ws_size,
                              hipStream_t stream) {
    const float* user_emb = (const float*)d_in[0];
    const float* item_emb = (const float*)d_in[1];
    const float* vals     = (const float*)d_in[2];
    const int*   rows     = (const int*)d_in[3];
    const int*   cols     = (const int*)d_in[4];
    const int*   users    = (const int*)d_in[5];
    const int*   items    = (const int*)d_in[6];
    float* out = (float*)d_out;

    const int nnz = in_sizes[2];
    const int np1 = (nnz + P1_C - 1) / P1_C;

    char* ws = (char*)d_ws;
    const size_t embB   = (size_t)N_TOTAL * LATENT * sizeof(u16);     // 19.2 MB
    const size_t accB   = (size_t)BATCH * LATENT * sizeof(float);     // 4 MB
    const size_t slabB  = (size_t)NB * CAP * sizeof(uint2);           // 38.4 MB
    const size_t klabB  = (size_t)NB * CAP * sizeof(u16);             // 9.6 MB
    const size_t edgeB  = (size_t)(nnz + 16) * sizeof(uint2);         // 32 MB + pad

    size_t off = 0;
    u16*   emb_a   = (u16*)  (ws + off); off += embB;
    u16*   emb_b   = (u16*)  (ws + off); off += embB;
    uint2* packed0 = (uint2*)(ws + off); off += slabB;
    u16*   klab    = (u16*)  (ws + off); off += klabB;
    uint2* edges   = (uint2*)(ws + off); off += edgeB;
    float* u_acc   = (float*)(ws + off); off += accB;
    float* i_acc   = (float*)(ws + off); off += accB;
    int*   rowptr  = (int*)  (ws + off); off += (size_t)(N_TOTAL + 1) * sizeof(int);
    int*   ccur    = (int*)  (ws + off); off += (size_t)(NB + 1) * sizeof(int);

    hipMemsetAsync(ccur, 0, (size_t)(NB + 1) * sizeof(int), stream);
    hipMemsetAsync(edges + nnz, 0, 16 * sizeof(uint2), stream);   // tail padding

    // A: partition1 + convert + init_acc with interleaved block->role mapping
    fatA_kernel<<<np1 + CVT_B + INIT_B, P1_T, 0, stream>>>(
        rows, cols, vals, ccur, packed0, klab,
        user_emb, item_emb, emb_a, users, items, u_acc, i_acc, nnz, np1);

    // B: per-bucket counting sort (self-scans bucket counts)
    partition2_kernel<<<NB, BROWS, 0, stream>>>(ccur, packed0, klab, edges, rowptr, nnz);

    // layer 1
    spmm_kernel<<<N_TOTAL / 8, 256, 0, stream>>>(rowptr, edges, emb_a, emb_b);
    // layer 2 + gather_acc(layer 1)
    spmm_gather_kernel<<<N_TOTAL / 8 + GATH_B, 256, 0, stream>>>(
        rowptr, edges, emb_b, emb_a, users, items, u_acc, i_acc, N_TOTAL / 8);
    // layer 3 (batch rows only) with layer-2 gather folded into the epilogue
    spmm_batch_kernel<<<(2 * BATCH) / 4, 256, 0, stream>>>(
        rowptr, edges, emb_a, users, items, u_acc, i_acc);

    dot_kernel<<<BATCH / 8, 512, 0, stream>>>(u_acc, i_acc, out);
}

// Round 13
// 285.544 us; speedup vs baseline: 1.0781x; 1.0781x over previous
//
#include <hip/hip_runtime.h>

#define NUM_USERS 100000
#define NUM_ITEMS 50000
#define N_TOTAL   150000
#define LATENT    64
#define BATCH     16384
#define BROWS     512                 // rows per bucket
#define NB        293                 // ceil(N_TOTAL / BROWS)
#define CAP       16384               // per-bucket slab capacity (count ~13.6k +- 120, +23 sigma)
#define P1_T      512                 // partition threads
#define P1_C      4096                // partition1 edges per block
#define CVT_B     2344                // convert blocks (2.4M float4 items, 2/thread)
#define INIT_B    512                 // init_acc blocks (BATCH*16 float4 threads)
#define GATH_B    1024                // gather blocks (BATCH*16 threads @256)

typedef unsigned int u32;
typedef unsigned short u16;

__device__ __forceinline__ u16 f32_to_bf16(float f) {
    u32 u = __float_as_uint(f);
    u32 r = (u + 0x7FFFu + ((u >> 16) & 1u)) >> 16;   // round-to-nearest-even
    return (u16)r;
}
__device__ __forceinline__ float bf16_lo(u32 w) { return __uint_as_float(w << 16); }
__device__ __forceinline__ float bf16_hi(u32 w) { return __uint_as_float(w & 0xFFFF0000u); }

__device__ __forceinline__ void fma4(float acc[4], uint2 xv, float v) {
    acc[0] = fmaf(v, bf16_lo(xv.x), acc[0]);
    acc[1] = fmaf(v, bf16_hi(xv.x), acc[1]);
    acc[2] = fmaf(v, bf16_lo(xv.y), acc[2]);
    acc[3] = fmaf(v, bf16_hi(xv.y), acc[3]);
}

// ---- wave-level inclusive scan (64 lanes) ----
__device__ __forceinline__ int wave_incl_scan(int v, int lane) {
    #pragma unroll
    for (int d = 1; d < 64; d <<= 1) {
        int t = __shfl_up(v, d, 64);
        if (lane >= d) v += t;
    }
    return v;
}

// ---- 512-thread block exclusive scan; wsum is LDS int[8]; 2 barriers ----
__device__ __forceinline__ int block_excl_scan_512(int v, int t, int* wsum) {
    int lane = t & 63, w = t >> 6;
    int incl = wave_incl_scan(v, lane);
    if (lane == 63) wsum[w] = incl;
    __syncthreads();
    if (t == 0) {
        int acc = 0;
        #pragma unroll
        for (int k = 0; k < 8; ++k) { int c = wsum[k]; wsum[k] = acc; acc += c; }
    }
    __syncthreads();
    return wsum[w] + incl - v;
}

// =================== kernel 1: partition pass 1 (pure, high-LDS) ===================
__global__ void __launch_bounds__(P1_T)
p1_kernel(const int* __restrict__ rows, const int* __restrict__ cols,
          const float* __restrict__ vals,
          int* __restrict__ ccur, uint2* __restrict__ packed0, u16* __restrict__ klab,
          int nnz) {
    __shared__ u32 skey[P1_C];
    __shared__ u32 sval[P1_C];
    __shared__ u16 sbucket[P1_C];
    __shared__ int cnt[NB];
    __shared__ int lstart[NB];
    __shared__ int lcur[NB];
    __shared__ int gbase[NB];
    __shared__ int wsum[8];

    int t = threadIdx.x;
    int base = blockIdx.x * P1_C;
    int chunkN = nnz - base; if (chunkN > P1_C) chunkN = P1_C;

    for (int i = t; i < NB; i += P1_T) cnt[i] = 0;
    __syncthreads();

    int er[8]; u32 ek[8]; u32 ev[8];
    #pragma unroll
    for (int k = 0; k < 8; ++k) {
        int e = base + k * P1_T + t;
        bool ok = (k * P1_T + t) < chunkN;
        int r = ok ? rows[e] : 0;
        er[k] = ok ? (r >> 9) : -1;
        if (ok) {
            ek[k] = (u32)cols[e] | ((u32)(r & (BROWS - 1)) << 18);
            ev[k] = __float_as_uint(vals[e]);
            atomicAdd(&cnt[er[k]], 1);
        }
    }
    __syncthreads();

    int v = (t < NB) ? cnt[t] : 0;
    int excl = block_excl_scan_512(v, t, wsum);
    if (t < NB) {
        lstart[t] = excl;
        lcur[t] = excl;
        gbase[t] = v ? atomicAdd(&ccur[t], v) : 0;
    }
    __syncthreads();

    #pragma unroll
    for (int k = 0; k < 8; ++k) {
        if (er[k] >= 0) {
            int pos = atomicAdd(&lcur[er[k]], 1);
            skey[pos] = ek[k];
            sval[pos] = ev[k];
            sbucket[pos] = (u16)er[k];
        }
    }
    __syncthreads();

    for (int idx = t; idx < chunkN; idx += P1_T) {
        int b2 = sbucket[idx];
        size_t gp = (size_t)b2 * CAP + gbase[b2] + (idx - lstart[b2]);
        u32 key = skey[idx];
        packed0[gp] = make_uint2(key, sval[idx]);
        klab[gp] = (u16)(key >> 18);
    }
}

// =================== kernel 2 (fatB): p2 | convert | init_acc ===================
// p2 has only 293 blocks (~1.14/CU); convert/init blocks fill the idle CUs and
// overlap for real (fatB's static LDS is tiny, ~4.2 KB, so co-residency is high).
__global__ void __launch_bounds__(P1_T)
fatB_kernel(const int* __restrict__ ccur, const uint2* __restrict__ packed0,
            const u16* __restrict__ klab,
            uint2* __restrict__ edges, int* __restrict__ rowptr,
            const float* __restrict__ ue, const float* __restrict__ ie,
            u16* __restrict__ emb0,
            const int* __restrict__ users, const int* __restrict__ items,
            float* __restrict__ u_acc, float* __restrict__ i_acc,
            int nnz) {
    __shared__ int cnt[BROWS];
    __shared__ int cur[BROWS];
    __shared__ int wsum[8];
    __shared__ int sOutb;

    int t = threadIdx.x;
    int bid = blockIdx.x;

    if (bid < NB) {
        // ---------------- partition pass 2 role ----------------
        int b = bid;
        // self-scan of the 293 bucket counts -> this bucket's output base
        int cv = (t < NB) ? ccur[t] : 0;
        int cexcl = block_excl_scan_512(cv, t, wsum);
        if (t == b) sOutb = cexcl;
        cnt[t] = 0;
        __syncthreads();
        int outb = sOutb;
        int count = ccur[b];

        const uint2* src = packed0 + (size_t)b * CAP;
        const u16*   kl  = klab + (size_t)b * CAP;
        // histogram from the compact 2B key stream
        for (int i = t; i < count; i += 2 * BROWS) {
            u16 k0 = kl[i];
            int i2 = i + BROWS;
            if (i2 < count) {
                u16 k1 = kl[i2];
                atomicAdd(&cnt[k0], 1);
                atomicAdd(&cnt[k1], 1);
            } else {
                atomicAdd(&cnt[k0], 1);
            }
        }
        __syncthreads();
        int v = cnt[t];
        int excl = block_excl_scan_512(v, t, wsum);
        cur[t] = excl;
        int r = (b << 9) + t;
        if (r < N_TOTAL) rowptr[r] = outb + excl;
        if (b == NB - 1 && t == 0) rowptr[N_TOTAL] = nnz;
        __syncthreads();
        for (int i = t; i < count; i += 2 * BROWS) {
            uint2 p0 = src[i];
            int i2 = i + BROWS;
            if (i2 < count) {
                uint2 p1 = src[i2];
                int pos0 = outb + atomicAdd(&cur[p0.x >> 18], 1);
                int pos1 = outb + atomicAdd(&cur[p1.x >> 18], 1);
                edges[pos0] = make_uint2(p0.x & 0x3FFFFu, p0.y);
                edges[pos1] = make_uint2(p1.x & 0x3FFFFu, p1.y);
            } else {
                int pos0 = outb + atomicAdd(&cur[p0.x >> 18], 1);
                edges[pos0] = make_uint2(p0.x & 0x3FFFFu, p0.y);
            }
        }
    } else if (bid < NB + CVT_B) {
        // ---------------- convert role: f32 -> bf16, 2 float4 items per thread ----------------
        const int n4 = N_TOTAL * LATENT / 4;
        const int ub = NUM_USERS * LATENT / 4;
        const int T  = CVT_B * P1_T;
        int g = (bid - NB) * P1_T + t;
        #pragma unroll
        for (int rep = 0; rep < 2; ++rep) {
            int i = g + rep * T;
            if (i < n4) {
                float4 f = (i < ub) ? reinterpret_cast<const float4*>(ue)[i]
                                    : reinterpret_cast<const float4*>(ie)[i - ub];
                ushort4 o;
                o.x = f32_to_bf16(f.x); o.y = f32_to_bf16(f.y);
                o.z = f32_to_bf16(f.z); o.w = f32_to_bf16(f.w);
                reinterpret_cast<ushort4*>(emb0)[i] = o;
            }
        }
    } else {
        // ---------------- init_acc role: float4 per thread ----------------
        int g = (bid - NB - CVT_B) * P1_T + t;      // 0 .. BATCH*16-1
        int b = g >> 4, dq = (g & 15) << 2;
        if (b < BATCH) {
            reinterpret_cast<float4*>(u_acc + (size_t)b * LATENT + dq)[0] =
                reinterpret_cast<const float4*>(ue + (size_t)users[b] * LATENT + dq)[0];
            reinterpret_cast<float4*>(i_acc + (size_t)b * LATENT + dq)[0] =
                reinterpret_cast<const float4*>(ie + (size_t)items[b] * LATENT + dq)[0];
        }
    }
}

// ---- row tail: 8-edge then guarded 4-edge loops (no reduce) ----
__device__ __forceinline__ void row_tail(const uint2* __restrict__ edges,
                                         const u16* __restrict__ x,
                                         int i, int e, int j, int q, float acc[4]) {
    for (; i + 8 <= e; i += 8) {
        uint2 e0 = edges[i + j];
        uint2 e1 = edges[i + 4 + j];
        uint2 x0 = *reinterpret_cast<const uint2*>(x + (size_t)e0.x * LATENT + q);
        uint2 x1 = *reinterpret_cast<const uint2*>(x + (size_t)e1.x * LATENT + q);
        fma4(acc, x0, __uint_as_float(e0.y));
        fma4(acc, x1, __uint_as_float(e1.y));
    }
    for (; i < e; i += 4) {
        // memory-safe: edges has >=16 zero-padded entries past nnz; reading the
        // next row's edge is fine because v is forced to 0 for out-of-row slots
        uint2 e0 = edges[i + j];
        float v0 = (i + j < e) ? __uint_as_float(e0.y) : 0.f;
        uint2 x0 = *reinterpret_cast<const uint2*>(x + (size_t)e0.x * LATENT + q);
        fma4(acc, x0, v0);
    }
}

// ---- single-row SpMM core (used by batch kernel) ----
__device__ __forceinline__ void spmm_row(const uint2* __restrict__ edges,
                                         const u16* __restrict__ x,
                                         int s, int e, int lane, float acc[4]) {
    int j = lane >> 4;
    int q = (lane & 15) << 2;
    acc[0] = acc[1] = acc[2] = acc[3] = 0.f;
    int i = s;
    for (; i + 16 <= e; i += 16) {
        uint2 e0 = edges[i + j];
        uint2 e1 = edges[i + 4 + j];
        uint2 e2 = edges[i + 8 + j];
        uint2 e3 = edges[i + 12 + j];
        uint2 x0 = *reinterpret_cast<const uint2*>(x + (size_t)e0.x * LATENT + q);
        uint2 x1 = *reinterpret_cast<const uint2*>(x + (size_t)e1.x * LATENT + q);
        uint2 x2 = *reinterpret_cast<const uint2*>(x + (size_t)e2.x * LATENT + q);
        uint2 x3 = *reinterpret_cast<const uint2*>(x + (size_t)e3.x * LATENT + q);
        fma4(acc, x0, __uint_as_float(e0.y));
        fma4(acc, x1, __uint_as_float(e1.y));
        fma4(acc, x2, __uint_as_float(e2.y));
        fma4(acc, x3, __uint_as_float(e3.y));
    }
    row_tail(edges, x, i, e, j, q, acc);
    #pragma unroll
    for (int k = 0; k < 4; ++k) {
        acc[k] += __shfl_xor(acc[k], 16, 64);
        acc[k] += __shfl_xor(acc[k], 32, 64);
    }
}

// ---- two-row SpMM body (writes bf16 rows r0, r0+1) ----
__device__ __forceinline__ void spmm_two_rows(const int* __restrict__ rowptr,
                                              const uint2* __restrict__ edges,
                                              const u16* __restrict__ x,
                                              u16* __restrict__ y,
                                              int wid, int lane) {
    int r0 = wid * 2;
    int j = lane >> 4;
    int q = (lane & 15) << 2;
    int i0 = rowptr[r0];
    int e0 = rowptr[r0 + 1];
    int i1 = e0;
    int e1 = rowptr[r0 + 2];
    float a0[4] = {0.f, 0.f, 0.f, 0.f};
    float a1[4] = {0.f, 0.f, 0.f, 0.f};

    while (i0 + 8 <= e0 && i1 + 8 <= e1) {
        uint2 p00 = edges[i0 + j];
        uint2 p01 = edges[i0 + 4 + j];
        uint2 p10 = edges[i1 + j];
        uint2 p11 = edges[i1 + 4 + j];
        uint2 g00 = *reinterpret_cast<const uint2*>(x + (size_t)p00.x * LATENT + q);
        uint2 g01 = *reinterpret_cast<const uint2*>(x + (size_t)p01.x * LATENT + q);
        uint2 g10 = *reinterpret_cast<const uint2*>(x + (size_t)p10.x * LATENT + q);
        uint2 g11 = *reinterpret_cast<const uint2*>(x + (size_t)p11.x * LATENT + q);
        fma4(a0, g00, __uint_as_float(p00.y));
        fma4(a0, g01, __uint_as_float(p01.y));
        fma4(a1, g10, __uint_as_float(p10.y));
        fma4(a1, g11, __uint_as_float(p11.y));
        i0 += 8;
        i1 += 8;
    }
    row_tail(edges, x, i0, e0, j, q, a0);
    row_tail(edges, x, i1, e1, j, q, a1);

    #pragma unroll
    for (int k = 0; k < 4; ++k) {
        a0[k] += __shfl_xor(a0[k], 16, 64);
        a0[k] += __shfl_xor(a0[k], 32, 64);
        a1[k] += __shfl_xor(a1[k], 16, 64);
        a1[k] += __shfl_xor(a1[k], 32, 64);
    }
    if (lane < 16) {
        u32 w0 = (u32)f32_to_bf16(a0[0]) | ((u32)f32_to_bf16(a0[1]) << 16);
        u32 w1 = (u32)f32_to_bf16(a0[2]) | ((u32)f32_to_bf16(a0[3]) << 16);
        *reinterpret_cast<uint2*>(y + (size_t)r0 * LATENT + (lane << 2)) = make_uint2(w0, w1);
        u32 w2 = (u32)f32_to_bf16(a1[0]) | ((u32)f32_to_bf16(a1[1]) << 16);
        u32 w3 = (u32)f32_to_bf16(a1[2]) | ((u32)f32_to_bf16(a1[3]) << 16);
        *reinterpret_cast<uint2*>(y + (size_t)(r0 + 1) * LATENT + (lane << 2)) = make_uint2(w2, w3);
    }
}

// ---- gather-acc role body: uint2 (4 bf16 dims) per thread ----
__device__ __forceinline__ void gather_role(const u16* __restrict__ emb,
                                            const int* __restrict__ users,
                                            const int* __restrict__ items,
                                            float* __restrict__ u_acc,
                                            float* __restrict__ i_acc, int g) {
    int b = g >> 4, dq = (g & 15) << 2;
    if (b >= BATCH) return;
    uint2 xu = *reinterpret_cast<const uint2*>(emb + (size_t)users[b] * LATENT + dq);
    uint2 xi = *reinterpret_cast<const uint2*>(emb + ((size_t)items[b] + NUM_USERS) * LATENT + dq);
    float4* pu = reinterpret_cast<float4*>(u_acc + (size_t)b * LATENT + dq);
    float4* pi = reinterpret_cast<float4*>(i_acc + (size_t)b * LATENT + dq);
    float4 ou = *pu, oi = *pi;
    ou.x += bf16_lo(xu.x); ou.y += bf16_hi(xu.x); ou.z += bf16_lo(xu.y); ou.w += bf16_hi(xu.y);
    oi.x += bf16_lo(xi.x); oi.y += bf16_hi(xi.x); oi.z += bf16_lo(xi.y); oi.w += bf16_hi(xi.y);
    *pu = ou; *pi = oi;
}

// ---- spmm layer 1 (pure) ----
__global__ void spmm_kernel(const int* __restrict__ rowptr, const uint2* __restrict__ edges,
                            const u16* __restrict__ x, u16* __restrict__ y) {
    int wid = blockIdx.x * 4 + (threadIdx.x >> 6);
    spmm_two_rows(rowptr, edges, x, y, wid, threadIdx.x & 63);
}

// ---- spmm layer 2 + gather_acc(layer-1 output) fat kernel (disjoint buffers: safe) ----
__global__ void spmm_gather_kernel(const int* __restrict__ rowptr, const uint2* __restrict__ edges,
                                   const u16* __restrict__ x, u16* __restrict__ y,
                                   const int* __restrict__ users, const int* __restrict__ items,
                                   float* __restrict__ u_acc, float* __restrict__ i_acc,
                                   int nspmm) {
    int bid = blockIdx.x;
    if (bid < nspmm) {
        int wid = bid * 4 + (threadIdx.x >> 6);
        spmm_two_rows(rowptr, edges, x, y, wid, threadIdx.x & 63);
    } else {
        gather_role(x, users, items, u_acc, i_acc, (bid - nspmm) * 256 + threadIdx.x);
    }
}

// ---- layer 3: batch-rows-only SpMM with layer-2 gather FOLDED into the epilogue ----
// (single RMW per u_acc/i_acc address in this kernel -> no race)
__global__ void spmm_batch_kernel(const int* __restrict__ rowptr, const uint2* __restrict__ edges,
                                  const u16* __restrict__ x,
                                  const int* __restrict__ users, const int* __restrict__ items,
                                  float* __restrict__ u_acc, float* __restrict__ i_acc) {
    int slot = blockIdx.x * 4 + (threadIdx.x >> 6);   // 0 .. 2*BATCH-1
    int lane = threadIdx.x & 63;
    int row = (slot < BATCH) ? users[slot] : (NUM_USERS + items[slot - BATCH]);
    int s = rowptr[row], e = rowptr[row + 1];
    float acc[4];
    spmm_row(edges, x, s, e, lane, acc);
    if (lane < 16) {
        // layer-2 contribution: this row's own embedding (input x of this kernel)
        uint2 xr = *reinterpret_cast<const uint2*>(x + (size_t)row * LATENT + (lane << 2));
        float* dst = (slot < BATCH) ? (u_acc + (size_t)slot * LATENT)
                                    : (i_acc + (size_t)(slot - BATCH) * LATENT);
        float4* p = reinterpret_cast<float4*>(dst + (lane << 2));
        float4 old = *p;
        old.x += acc[0] + bf16_lo(xr.x);
        old.y += acc[1] + bf16_hi(xr.x);
        old.z += acc[2] + bf16_lo(xr.y);
        old.w += acc[3] + bf16_hi(xr.y);
        *p = old;
    }
}

// ---- gamma[b] = dot(u_acc[b], i_acc[b]) / 16 ; 8 rows per 512-thread block ----
__global__ void dot_kernel(const float* __restrict__ u_acc,
                           const float* __restrict__ i_acc,
                           float* __restrict__ out) {
    int b = blockIdx.x * 8 + (threadIdx.x >> 6);
    int d = threadIdx.x & 63;
    float p = u_acc[b * 64 + d] * i_acc[b * 64 + d];
    #pragma unroll
    for (int off = 32; off; off >>= 1) p += __shfl_down(p, off, 64);
    if (d == 0) out[b] = p * (1.0f / 16.0f);
}

extern "C" void kernel_launch(void* const* d_in, const int* in_sizes, int n_in,
                              void* d_out, int out_size, void* d_ws, size_t ws_size,
                              hipStream_t stream) {
    const float* user_emb = (const float*)d_in[0];
    const float* item_emb = (const float*)d_in[1];
    const float* vals     = (const float*)d_in[2];
    const int*   rows     = (const int*)d_in[3];
    const int*   cols     = (const int*)d_in[4];
    const int*   users    = (const int*)d_in[5];
    const int*   items    = (const int*)d_in[6];
    float* out = (float*)d_out;

    const int nnz = in_sizes[2];
    const int np1 = (nnz + P1_C - 1) / P1_C;

    char* ws = (char*)d_ws;
    const size_t embB   = (size_t)N_TOTAL * LATENT * sizeof(u16);     // 19.2 MB
    const size_t accB   = (size_t)BATCH * LATENT * sizeof(float);     // 4 MB
    const size_t slabB  = (size_t)NB * CAP * sizeof(uint2);           // 38.4 MB
    const size_t klabB  = (size_t)NB * CAP * sizeof(u16);             // 9.6 MB
    const size_t edgeB  = (size_t)(nnz + 16) * sizeof(uint2);         // 32 MB + pad

    size_t off = 0;
    u16*   emb_a   = (u16*)  (ws + off); off += embB;
    u16*   emb_b   = (u16*)  (ws + off); off += embB;
    uint2* packed0 = (uint2*)(ws + off); off += slabB;
    u16*   klab    = (u16*)  (ws + off); off += klabB;
    uint2* edges   = (uint2*)(ws + off); off += edgeB;
    float* u_acc   = (float*)(ws + off); off += accB;
    float* i_acc   = (float*)(ws + off); off += accB;
    int*   rowptr  = (int*)  (ws + off); off += (size_t)(N_TOTAL + 1) * sizeof(int);
    int*   ccur    = (int*)  (ws + off); off += (size_t)(NB + 1) * sizeof(int);

    hipMemsetAsync(ccur, 0, (size_t)(NB + 1) * sizeof(int), stream);
    hipMemsetAsync(edges + nnz, 0, 16 * sizeof(uint2), stream);   // tail padding

    // 1: partition pass 1 (pure)
    p1_kernel<<<np1, P1_T, 0, stream>>>(rows, cols, vals, ccur, packed0, klab, nnz);

    // 2 (fatB): p2 (293 blocks) + convert + init_acc — aux fills the CUs p2 leaves idle
    fatB_kernel<<<NB + CVT_B + INIT_B, P1_T, 0, stream>>>(
        ccur, packed0, klab, edges, rowptr,
        user_emb, item_emb, emb_a, users, items, u_acc, i_acc, nnz);

    // layer 1
    spmm_kernel<<<N_TOTAL / 8, 256, 0, stream>>>(rowptr, edges, emb_a, emb_b);
    // layer 2 + gather_acc(layer 1)
    spmm_gather_kernel<<<N_TOTAL / 8 + GATH_B, 256, 0, stream>>>(
        rowptr, edges, emb_b, emb_a, users, items, u_acc, i_acc, N_TOTAL / 8);
    // layer 3 (batch rows only) with layer-2 gather folded into the epilogue
    spmm_batch_kernel<<<(2 * BATCH) / 4, 256, 0, stream>>>(
        rowptr, edges, emb_a, users, items, u_acc, i_acc);

    dot_kernel<<<BATCH / 8, 512, 0, stream>>>(u_acc, i_acc, out);
}